// Round 8
// baseline (5414.123 us; speedup 1.0000x reference)
//
#include <hip/hip_runtime.h>
#include <hip/hip_bf16.h>
#include <string.h>

// Problem constants
#define B_ 64
#define T_ 256
#define F_ 64
#define U_ 512
#define G4_ 2048     // 4*U
#define KTOT 576     // F + U
#define KSTEPS 18    // KTOT/32

typedef __attribute__((ext_vector_type(8))) short short8;
typedef __attribute__((ext_vector_type(4))) float v4f;
typedef __attribute__((ext_vector_type(4))) int i4;
typedef unsigned short u16;

__device__ __forceinline__ float bf2f(u16 b) {
    unsigned int x = ((unsigned int)b) << 16;
    float f; memcpy(&f, &x, 4); return f;
}
__device__ __forceinline__ u16 f2bf(float f) {
    __hip_bfloat16 h = __float2bfloat16(f);
    u16 b; memcpy(&b, &h, 2); return b;
}
__device__ __forceinline__ float sigmoidf_(float x) { return 1.f / (1.f + __expf(-x)); }
__device__ __forceinline__ float tanhf_(float x) {   // clamped exp form: no NaN, fast
    float xc = fminf(15.f, fmaxf(-15.f, x));
    float e = __expf(2.f * xc);
    return (e - 1.f) / (e + 1.f);
}

// Dtype-flexible element load: fg=1 -> fp32, fg=0 -> bf16.
__device__ __forceinline__ float ldany(const void* p, size_t i, int fg) {
    return fg ? ((const float*)p)[i] : bf2f(((const u16*)p)[i]);
}

// Workspace layout (bytes; offsets 64-aligned).
#define WS_FLAG   0             // int dtype-flag @0
#define WS_XB     64            // bf16 [T][B][F]          2,097,152
#define WS_WP     2097216       // bf16 packed weights     2,359,296
#define WS_H2     4456512       // bf16 [2][8 rg][8 rows][512 units]  131,072
#define WS_DOT    4718656       // fp32 [B][T]                65,536
#define WS_BIASF  4784192       // fp32 [4U]                   8,192
#define WS_ATTWF  4792384       // fp32 [T][T]               262,144
#define WS_ATTBF  5054528       // fp32 [T]                    1,024
#define WS_OUTWF  5055552       // fp32 [U]                    2,048
#define WS_OUTBF  5057600       // fp32 [1]                       64
#define WS_NEED   5057920

// ---------------------------------------------------------------------------
// Kernel 0: dtype detection (flag: 1 = fp32 inputs, 0 = bf16).
// ---------------------------------------------------------------------------
__global__ __launch_bounds__(256) void detect(const unsigned int* __restrict__ w,
                                              int* __restrict__ flag) {
    __shared__ int votes;
    if (threadIdx.x == 0) votes = 0;
    __syncthreads();
    unsigned int v = w[threadIdx.x];
    int e = (v >> 7) & 0xFF;
    if (e >= 100 && e <= 135) atomicAdd(&votes, 1);
    __syncthreads();
    if (threadIdx.x == 0) *flag = (votes < 200) ? 1 : 0;
}

// ---------------------------------------------------------------------------
// Kernel 1: canonicalize inputs.  x -> xb bf16 [T][B][F]; small arrays ->
// fp32; dot -> 0; h2 ping-pong -> 0 (tag 0 == stale for every expected tag).
// ---------------------------------------------------------------------------
__global__ __launch_bounds__(256) void convert(const void* __restrict__ x,
                                               const void* __restrict__ bias,
                                               const void* __restrict__ attW,
                                               const void* __restrict__ attb,
                                               const void* __restrict__ outW,
                                               const void* __restrict__ outb,
                                               const int* __restrict__ flag,
                                               u16* __restrict__ xb,
                                               float* __restrict__ biasf,
                                               float* __restrict__ attWf,
                                               float* __restrict__ attbf,
                                               float* __restrict__ outWf,
                                               float* __restrict__ outbf,
                                               float* __restrict__ dot,
                                               unsigned int* __restrict__ h2z) {
    int fg = *flag;
    size_t i = (size_t)blockIdx.x * 256 + threadIdx.x;
    if (i < 1048576) {
        float v = ldany(x, i, fg);
        int b = (int)(i >> 14), t = (int)((i >> 6) & 255), f = (int)(i & 63);
        xb[((size_t)t * B_ + b) * F_ + f] = f2bf(v);
        return;
    }
    i -= 1048576;
    if (i < 2048)  { biasf[i] = ldany(bias, i, fg); return; }
    i -= 2048;
    if (i < 65536) { attWf[i] = ldany(attW, i, fg); return; }
    i -= 65536;
    if (i < 256)   { attbf[i] = ldany(attb, i, fg); return; }
    i -= 256;
    if (i < 512)   { outWf[i] = ldany(outW, i, fg); return; }
    i -= 512;
    if (i < 1)     { outbf[i] = ldany(outb, i, fg); return; }
    i -= 1;
    if (i < 16384) { dot[i] = 0.f; return; }
    i -= 16384;
    if (i < 32768) { h2z[i] = 0u; return; }
}

// ---------------------------------------------------------------------------
// Kernel 2: pack [kernel; rec_kernel] into MFMA-B fragments, cols c'=4u+gate.
// Lane l of fragment (nt, ks) supplies B[k=ks*32+(l>>4)*8+j][col=nt*16+(l&15)].
// ---------------------------------------------------------------------------
__global__ __launch_bounds__(256) void pack_w(const void* __restrict__ kin,
                                              const void* __restrict__ krec,
                                              const int* __restrict__ flag,
                                              u16* __restrict__ Wp) {
    int fg = *flag;
    int gid = blockIdx.x * 256 + threadIdx.x;   // grid = 576*256 == 128*18*64
    int lane = gid & 63;
    int frag = gid >> 6;
    int nt = frag / KSTEPS;
    int ks = frag - nt * KSTEPS;
    int kbase = ks * 32 + (lane >> 4) * 8;
    int cp = nt * 16 + (lane & 15);
    int u = cp >> 2, gate = cp & 3;
    int C = gate * U_ + u;
    short8 v;
    for (int j = 0; j < 8; j++) {
        int k = kbase + j;
        float w = (k < F_) ? ldany(kin, (size_t)k * G4_ + C, fg)
                           : ldany(krec, (size_t)(k - F_) * G4_ + C, fg);
        v[j] = (short)f2bf(w);
    }
    *reinterpret_cast<short8*>(Wp + (size_t)gid * 8) = v;
}

// 16 coherent 16B loads, all in flight, one drain.  FLG = cache-scope flags.
#define HLOAD16(FLG)                                                        \
    asm volatile(                                                           \
        "global_load_dwordx4 %0,  %16, off " FLG "\n\t"                     \
        "global_load_dwordx4 %1,  %16, off offset:64 " FLG "\n\t"           \
        "global_load_dwordx4 %2,  %16, off offset:128 " FLG "\n\t"          \
        "global_load_dwordx4 %3,  %16, off offset:192 " FLG "\n\t"          \
        "global_load_dwordx4 %4,  %16, off offset:256 " FLG "\n\t"          \
        "global_load_dwordx4 %5,  %16, off offset:320 " FLG "\n\t"          \
        "global_load_dwordx4 %6,  %16, off offset:384 " FLG "\n\t"          \
        "global_load_dwordx4 %7,  %16, off offset:448 " FLG "\n\t"          \
        "global_load_dwordx4 %8,  %16, off offset:512 " FLG "\n\t"          \
        "global_load_dwordx4 %9,  %16, off offset:576 " FLG "\n\t"          \
        "global_load_dwordx4 %10, %16, off offset:640 " FLG "\n\t"          \
        "global_load_dwordx4 %11, %16, off offset:704 " FLG "\n\t"          \
        "global_load_dwordx4 %12, %16, off offset:768 " FLG "\n\t"          \
        "global_load_dwordx4 %13, %16, off offset:832 " FLG "\n\t"          \
        "global_load_dwordx4 %14, %16, off offset:896 " FLG "\n\t"          \
        "global_load_dwordx4 %15, %16, off offset:960 " FLG "\n\t"          \
        "s_waitcnt vmcnt(0)"                                                \
        : "=v"(f0), "=v"(f1), "=v"(f2),  "=v"(f3),                          \
          "=v"(f4), "=v"(f5), "=v"(f6),  "=v"(f7),                          \
          "=v"(f8), "=v"(f9), "=v"(f10), "=v"(f11),                         \
          "=v"(f12),"=v"(f13),"=v"(f14), "=v"(f15)                          \
        : "v"(bp)                                                           \
        : "memory")

// ---------------------------------------------------------------------------
// Kernel 3: PERSISTENT LSTM, XCD-LOCAL EXCHANGE, WAVE-AUTONOMOUS.
// Grid 256 x 256.  rg = blk&7 (maps to XCD via round-robin dispatch; a
// heuristic only -- correctness never depends on it), owns batch rows
// [8rg,8rg+8); gu = blk>>3 owns units [16gu,16gu+16); wave w owns n-tile
// 4gu+w (4 units).  Weights live in 72 VGPRs/wave (no LDS, loaded once).
// h exchange: producers DUAL-store (normal -> own L2; sc0+sc1 -> IC);
// consumers poll with sc0 (L2-local fast path), falling back to sc0+sc1
// after 16 misses.  In-band LSB tags (period-2) gate freshness per dword.
// No __syncthreads anywhere in the loop: gate transpose via shuffles,
// per-wave dot buffers.  Mirror rows (A rows 8-15) are exec-masked off the
// polls and zero-filled.  c state: 4 registers/lane (quad-uniform).
// ---------------------------------------------------------------------------
__global__ __launch_bounds__(256, 1) void lstm_persist(const u16* __restrict__ xb,
                                                       const float* __restrict__ biasf,
                                                       const float* __restrict__ outWf,
                                                       const u16* __restrict__ Wp,
                                                       u16* __restrict__ h2,
                                                       float* __restrict__ dot) {
    __shared__ float dp[4][32][8];            // per-wave dot partials, 4 KB

    int tid = threadIdx.x;
    int bid = blockIdx.x;
    int rg = bid & 7;                         // row-group (target: one XCD)
    int gu = bid >> 3;                        // unit-group
    int w = tid >> 6, l = tid & 63;
    int nt = 4 * gu + w;                      // this wave's n-tile

    // Weights into VGPRs: 18 fragments (72 VGPRs), loaded once.
    short8 W[KSTEPS];
    #pragma unroll
    for (int ks = 0; ks < KSTEPS; ks++)
        W[ks] = *reinterpret_cast<const short8*>(Wp + ((size_t)(nt * KSTEPS + ks) * 64 + l) * 8);

    // Per-lane constants.  Unit for this lane's quad; row base for D rows.
    int u_glob = gu * 16 + 4 * w + ((l & 15) >> 2);
    float bia = biasf[0 * U_ + u_glob];
    float bif = biasf[1 * U_ + u_glob];
    float big = biasf[2 * U_ + u_glob];
    float bio = biasf[3 * U_ + u_glob];
    float wout = outWf[u_glob];
    int rbase = (l >> 4) * 4;                 // D rows rbase..rbase+3 (valid <8)
    int row8 = (l & 15) & 7;                  // A row (mirrored for lanes 8-15 of each 16)
    int koff = (l >> 4) * 8;
    int brow = rg * 8 + row8;                 // global batch row for A
    bool act = ((l & 8) == 0);                // lanes that actually poll/load h
    float creg[4] = {0.f, 0.f, 0.f, 0.f};
    i4 f0 = {0,0,0,0}, f1 = {0,0,0,0}, f2 = {0,0,0,0}, f3 = {0,0,0,0},
       f4 = {0,0,0,0}, f5 = {0,0,0,0}, f6 = {0,0,0,0}, f7 = {0,0,0,0},
       f8 = {0,0,0,0}, f9 = {0,0,0,0}, f10 = {0,0,0,0}, f11 = {0,0,0,0},
       f12 = {0,0,0,0}, f13 = {0,0,0,0}, f14 = {0,0,0,0}, f15 = {0,0,0,0};

    for (int t = 0; t < T_; t++) {
        u16* hcur = h2 + (size_t)(t & 1) * 32768 + rg * 4096;
        const u16* hprev = h2 + (size_t)((t + 1) & 1) * 32768 + rg * 4096;
        unsigned int wtag = ((unsigned)(t >> 1) & 1u) ^ 1u;
        unsigned int rpat = ((((unsigned)(t - 1) >> 1) & 1u) ^ 1u) * 0x00010001u;

        // x fragments (plain loads; L2-hot).
        const u16* xrow = xb + ((size_t)t * B_ + brow) * F_;
        short8 a0 = *reinterpret_cast<const short8*>(xrow + koff);
        short8 a1 = *reinterpret_cast<const short8*>(xrow + 32 + koff);

        // Poll h_{t-1}: sc0 fast path (XCD-local L2), sc1 fallback after 16.
        if (t > 0) {
            const void* bp = (const void*)(hprev + (size_t)row8 * U_ + koff);
            int spins = 0;
            for (;;) {
                if (spins < 16) { if (act) { HLOAD16("sc0"); } }
                else            { if (act) { HLOAD16("sc0 sc1"); } }
                unsigned bad = 0;
                if (act) {
                    #define CK(f) bad |= (((unsigned)(f)[0]) ^ rpat) & 0x00010001u; \
                                  bad |= (((unsigned)(f)[1]) ^ rpat) & 0x00010001u; \
                                  bad |= (((unsigned)(f)[2]) ^ rpat) & 0x00010001u; \
                                  bad |= (((unsigned)(f)[3]) ^ rpat) & 0x00010001u;
                    CK(f0) CK(f1) CK(f2)  CK(f3)  CK(f4)  CK(f5)  CK(f6)  CK(f7)
                    CK(f8) CK(f9) CK(f10) CK(f11) CK(f12) CK(f13) CK(f14) CK(f15)
                    #undef CK
                }
                if (__ballot(bad == 0) == ~0ull) break;
                if (++spins > (1 << 15)) break;   // bailout: never hang
            }
        }

        // MFMA: two interleaved chains to pipeline the accumulator.
        v4f accA = {0.f, 0.f, 0.f, 0.f}, accB = {0.f, 0.f, 0.f, 0.f};
        accA = __builtin_amdgcn_mfma_f32_16x16x32_bf16(a0, W[0], accA, 0, 0, 0);
        accB = __builtin_amdgcn_mfma_f32_16x16x32_bf16(a1, W[1], accB, 0, 0, 0);
        if (t > 0) {
            i4 hf[16] = {f0,f1,f2,f3,f4,f5,f6,f7,f8,f9,f10,f11,f12,f13,f14,f15};
            #pragma unroll
            for (int ks = 2; ks < KSTEPS; ks += 2) {
                accA = __builtin_amdgcn_mfma_f32_16x16x32_bf16(
                    *reinterpret_cast<const short8*>(&hf[ks - 2]), W[ks], accA, 0, 0, 0);
                accB = __builtin_amdgcn_mfma_f32_16x16x32_bf16(
                    *reinterpret_cast<const short8*>(&hf[ks - 1]), W[ks + 1], accB, 0, 0, 0);
            }
        }
        v4f acc = accA + accB;

        // Gate gather via shuffles (quad qb..qb+3 holds gates i,f,c,o of one
        // unit), elementwise update; quad-uniform c/h, no LDS, no syncs.
        int qb = l & ~3;
        float h_[4];
        #pragma unroll
        for (int rr = 0; rr < 4; rr++) {
            float gi = __shfl(acc[rr], qb + 0, 64);
            float gf = __shfl(acc[rr], qb + 1, 64);
            float gg = __shfl(acc[rr], qb + 2, 64);
            float go = __shfl(acc[rr], qb + 3, 64);
            float ig = sigmoidf_(gi + bia);
            float fg = sigmoidf_(gf + bif);
            float gc = tanhf_(gg + big);
            float og = sigmoidf_(go + bio);
            creg[rr] = fg * creg[rr] + ig * gc;
            h_[rr] = og * tanhf_(creg[rr]);
        }

        // Dual-store h (unit pair packed to dword, LSB tags): leader lanes
        // l in {0,8,16,24} store rows rbase..rbase+3 x units (u_glob, u_glob+1).
        float hpart[4];
        #pragma unroll
        for (int rr = 0; rr < 4; rr++) hpart[rr] = __shfl_xor(h_[rr], 4, 64);
        if ((l & 7) == 0 && l < 32) {
            #pragma unroll
            for (int rr = 0; rr < 4; rr++) {
                unsigned int h0 = ((unsigned)f2bf(h_[rr])   & 0xFFFEu) | wtag;
                unsigned int h1 = ((unsigned)f2bf(hpart[rr]) & 0xFFFEu) | wtag;
                unsigned int pk = h0 | (h1 << 16);
                void* sp = (void*)(hcur + (size_t)(rbase + rr) * U_ + u_glob);
                asm volatile("global_store_dword %0, %1, off" :: "v"(sp), "v"(pk) : "memory");
                asm volatile("global_store_dword %0, %1, off sc0 sc1" :: "v"(sp), "v"(pk) : "memory");
            }
        }

        // Dot partials: sum this wave's 4 units per row; buffer per-wave.
        #pragma unroll
        for (int rr = 0; rr < 4; rr++) {
            float s = h_[rr] * wout;
            s += __shfl_xor(s, 4, 64);
            s += __shfl_xor(s, 8, 64);
            if ((l & 15) == 0 && l < 32) dp[w][t & 31][rbase + rr] = s;
        }

        // Per-wave flush every 32 steps (no cross-wave coupling).
        if ((t & 31) == 31) {
            int t0 = t - 31;
            #pragma unroll
            for (int j = 0; j < 4; j++) {
                int idx = j * 64 + l;
                int tt = idx >> 3, row = idx & 7;
                atomicAdd(&dot[(size_t)(rg * 8 + row) * T_ + (t0 + tt)], dp[w][tt][row]);
            }
        }
    }
}

// ---------------------------------------------------------------------------
// Kernel 4: finale (unchanged).
// ---------------------------------------------------------------------------
__global__ __launch_bounds__(256) void finale(const float* __restrict__ attWf,
                                              const float* __restrict__ attbf,
                                              const float* __restrict__ outWf,
                                              const float* __restrict__ outbf,
                                              const float* __restrict__ dot,
                                              const int* __restrict__ flag,
                                              void* __restrict__ out) {
    __shared__ float red[256];
    int t = blockIdx.x, tid = threadIdx.x;
    int fg = *flag;

    float v = (tid < t) ? attWf[(size_t)t * T_ + tid] : 0.f;
    red[tid] = v; __syncthreads();
    for (int s = 128; s > 0; s >>= 1) { if (tid < s) red[tid] += red[tid + s]; __syncthreads(); }
    float coef = (t == 0) ? 1.f : red[0];
    __syncthreads();
    red[tid] = outWf[tid] + outWf[tid + 256]; __syncthreads();
    for (int s = 128; s > 0; s >>= 1) { if (tid < s) red[tid] += red[tid + s]; __syncthreads(); }
    float sumW = red[0];

    float base = ((t == 0) ? 0.f : attbf[t]) * sumW + outbf[0];

    if (tid < B_) {
        float s = sigmoidf_(coef * dot[(size_t)tid * T_ + t] + base);
        size_t idx = (size_t)tid * T_ + t;
        if (fg) ((float*)out)[idx] = s;
        else    ((u16*)out)[idx] = f2bf(s);
    }
}

// ---------------------------------------------------------------------------
extern "C" void kernel_launch(void* const* d_in, const int* in_sizes, int n_in,
                              void* d_out, int out_size, void* d_ws, size_t ws_size,
                              hipStream_t stream) {
    const void* x    = d_in[0];
    const void* kin  = d_in[1];
    const void* krec = d_in[2];
    const void* bias = d_in[3];
    const void* attW = d_in[4];
    const void* attb = d_in[5];
    const void* outW = d_in[6];
    const void* outb = d_in[7];

    if (ws_size < (size_t)WS_NEED) return;

    char* ws = (char*)d_ws;
    int*   flag  = (int*)(ws + WS_FLAG);
    u16*   xb    = (u16*)(ws + WS_XB);
    u16*   Wp    = (u16*)(ws + WS_WP);
    u16*   h2    = (u16*)(ws + WS_H2);
    float* dot   = (float*)(ws + WS_DOT);
    float* biasf = (float*)(ws + WS_BIASF);
    float* attWf = (float*)(ws + WS_ATTWF);
    float* attbf = (float*)(ws + WS_ATTBF);
    float* outWf = (float*)(ws + WS_OUTWF);
    float* outbf = (float*)(ws + WS_OUTBF);

    detect<<<1, 256, 0, stream>>>((const unsigned int*)kin, flag);
    convert<<<4556, 256, 0, stream>>>(x, bias, attW, attb, outW, outb, flag,
                                      xb, biasf, attWf, attbf, outWf, outbf, dot,
                                      (unsigned int*)h2);
    pack_w<<<576, 256, 0, stream>>>(kin, krec, flag, Wp);
    lstm_persist<<<256, 256, 0, stream>>>(xb, biasf, outWf, Wp, h2, dot);
    finale<<<256, 256, 0, stream>>>(attWf, attbf, outWf, outbf, dot, flag, d_out);
}

// Round 9
// 1241.331 us; speedup vs baseline: 4.3615x; 4.3615x over previous
//
#include <hip/hip_runtime.h>
#include <hip/hip_bf16.h>
#include <string.h>

// Problem constants
#define B_ 64
#define T_ 256
#define F_ 64
#define U_ 512
#define G4_ 2048     // 4*U
#define KTOT 576     // F + U
#define KSTEPS 18    // KTOT/32

typedef __attribute__((ext_vector_type(8))) short short8;
typedef __attribute__((ext_vector_type(4))) float v4f;
typedef __attribute__((ext_vector_type(4))) int i4;
typedef unsigned short u16;

__device__ __forceinline__ float bf2f(u16 b) {
    unsigned int x = ((unsigned int)b) << 16;
    float f; memcpy(&f, &x, 4); return f;
}
__device__ __forceinline__ u16 f2bf(float f) {
    __hip_bfloat16 h = __float2bfloat16(f);
    u16 b; memcpy(&b, &h, 2); return b;
}
__device__ __forceinline__ float sigmoidf_(float x) { return 1.f / (1.f + __expf(-x)); }
__device__ __forceinline__ float tanhf_(float x) {   // clamped exp form (R8-proven)
    float xc = fminf(15.f, fmaxf(-15.f, x));
    float e = __expf(2.f * xc);
    return (e - 1.f) / (e + 1.f);
}

// Dtype-flexible element load: fg=1 -> fp32, fg=0 -> bf16.
__device__ __forceinline__ float ldany(const void* p, size_t i, int fg) {
    return fg ? ((const float*)p)[i] : bf2f(((const u16*)p)[i]);
}

// Workspace layout (bytes; offsets 64-aligned).
#define WS_FLAG   0             // int dtype-flag @0
#define WS_XB     64            // bf16 [T][B][F]          2,097,152
#define WS_WP     2097216       // bf16 packed weights     2,359,296
#define WS_H2     4456512       // bf16 [2][B][U]            131,072
#define WS_DOT    4718656       // fp32 [B][T]                65,536
#define WS_BIASF  4784192       // fp32 [4U]                   8,192
#define WS_ATTWF  4792384       // fp32 [T][T]               262,144
#define WS_ATTBF  5054528       // fp32 [T]                    1,024
#define WS_OUTWF  5055552       // fp32 [U]                    2,048
#define WS_OUTBF  5057600       // fp32 [1]                       64
#define WS_NEED   5057920

// ---------------------------------------------------------------------------
// Kernel 0: dtype detection (flag: 1 = fp32 inputs, 0 = bf16).
// ---------------------------------------------------------------------------
__global__ __launch_bounds__(256) void detect(const unsigned int* __restrict__ w,
                                              int* __restrict__ flag) {
    __shared__ int votes;
    if (threadIdx.x == 0) votes = 0;
    __syncthreads();
    unsigned int v = w[threadIdx.x];
    int e = (v >> 7) & 0xFF;
    if (e >= 100 && e <= 135) atomicAdd(&votes, 1);
    __syncthreads();
    if (threadIdx.x == 0) *flag = (votes < 200) ? 1 : 0;
}

// ---------------------------------------------------------------------------
// Kernel 1: canonicalize inputs.  x -> xb bf16 [T][B][F]; small arrays ->
// fp32; dot -> 0; h2 ping-pong -> 0 (tag 0 == stale for every expected tag,
// and zeros are the correct h_{-1} at t=0 where the check is skipped).
// ---------------------------------------------------------------------------
__global__ __launch_bounds__(256) void convert(const void* __restrict__ x,
                                               const void* __restrict__ bias,
                                               const void* __restrict__ attW,
                                               const void* __restrict__ attb,
                                               const void* __restrict__ outW,
                                               const void* __restrict__ outb,
                                               const int* __restrict__ flag,
                                               u16* __restrict__ xb,
                                               float* __restrict__ biasf,
                                               float* __restrict__ attWf,
                                               float* __restrict__ attbf,
                                               float* __restrict__ outWf,
                                               float* __restrict__ outbf,
                                               float* __restrict__ dot,
                                               unsigned int* __restrict__ h2z) {
    int fg = *flag;
    size_t i = (size_t)blockIdx.x * 256 + threadIdx.x;
    if (i < 1048576) {
        float v = ldany(x, i, fg);
        int b = (int)(i >> 14), t = (int)((i >> 6) & 255), f = (int)(i & 63);
        xb[((size_t)t * B_ + b) * F_ + f] = f2bf(v);
        return;
    }
    i -= 1048576;
    if (i < 2048)  { biasf[i] = ldany(bias, i, fg); return; }
    i -= 2048;
    if (i < 65536) { attWf[i] = ldany(attW, i, fg); return; }
    i -= 65536;
    if (i < 256)   { attbf[i] = ldany(attb, i, fg); return; }
    i -= 256;
    if (i < 512)   { outWf[i] = ldany(outW, i, fg); return; }
    i -= 512;
    if (i < 1)     { outbf[i] = ldany(outb, i, fg); return; }
    i -= 1;
    if (i < 16384) { dot[i] = 0.f; return; }
    i -= 16384;
    if (i < 32768) { h2z[i] = 0u; return; }   // both h ping-pong buffers
}

// ---------------------------------------------------------------------------
// Kernel 2: pack [kernel; rec_kernel] into MFMA-B fragments, cols c'=4u+gate.
// Lane l of fragment (nt, ks) supplies B[k=ks*32+(l>>4)*8+j][col=nt*16+(l&15)].
// ---------------------------------------------------------------------------
__global__ __launch_bounds__(256) void pack_w(const void* __restrict__ kin,
                                              const void* __restrict__ krec,
                                              const int* __restrict__ flag,
                                              u16* __restrict__ Wp) {
    int fg = *flag;
    int gid = blockIdx.x * 256 + threadIdx.x;   // grid = 576*256 == 128*18*64
    int lane = gid & 63;
    int frag = gid >> 6;
    int nt = frag / KSTEPS;
    int ks = frag - nt * KSTEPS;
    int kbase = ks * 32 + (lane >> 4) * 8;
    int cp = nt * 16 + (lane & 15);
    int u = cp >> 2, gate = cp & 3;
    int C = gate * U_ + u;
    short8 v;
    for (int j = 0; j < 8; j++) {
        int k = kbase + j;
        float w = (k < F_) ? ldany(kin, (size_t)k * G4_ + C, fg)
                           : ldany(krec, (size_t)(k - F_) * G4_ + C, fg);
        v[j] = (short)f2bf(w);
    }
    *reinterpret_cast<short8*>(Wp + (size_t)gid * 8) = v;
}

// ---------------------------------------------------------------------------
// Kernel 3: PERSISTENT LSTM, BARRIER-FREE (R7 structure + R9 deltas).
// 64 blocks (block b owns hidden units [8b,8b+8)), 256 threads = 4 waves.
// Freshness of h is IN-BAND: every stored bf16 h has its LSB forced to
// tag(t) = ((t>>1)&1)^1 (alternates per buffer reuse; differs from 0-init).
// Consumers poll the h region itself (16 coherent 16B loads, one vmcnt) and
// accept when ALL 64 dwords carry the expected tag.  R9 deltas vs R7:
//   (1) s_sleep backoff after a failed poll round (cuts IC queue pressure),
//   (2) gbuf ping-pong -> only ONE __syncthreads per step (flush steps: 2),
//   (3) fast clamped-exp tanh in the elementwise chain.
// 2-buffer safety: overwriting buf[t&1] with h_{t+2} requires consuming all
// of h_{t+1}, which certifies every block stored h_{t+1}, which certifies
// every block finished reading buf[t&1].  c lives in 2 registers/thread.
// ---------------------------------------------------------------------------
__global__ __launch_bounds__(256, 1) void lstm_persist(const u16* __restrict__ xb,
                                                       const float* __restrict__ biasf,
                                                       const float* __restrict__ outWf,
                                                       const u16* __restrict__ Wp,
                                                       u16* __restrict__ h2,
                                                       float* __restrict__ dot) {
    __shared__ __align__(16) u16 Bs[KSTEPS * 2 * 64 * 8];   // 36 KB weights
    __shared__ __align__(16) float gbuf[2][64][36];         // 18 KB gate preacts, ping-pong
    __shared__ float dp[32][64];                            // 8 KB dot partials

    int tid = threadIdx.x;
    int b = blockIdx.x;

    // Stage the block's B-slice (n-tiles 2b, 2b+1) into LDS: 2304 16B chunks.
    for (int i = 0; i < 9; i++) {
        int chunk = i * 256 + tid;            // 0..2303
        int ks = chunk >> 7;
        int rem = chunk & 127;
        int tile = rem >> 6;
        int lane2 = rem & 63;
        int nt = 2 * b + tile;
        short8 v = *reinterpret_cast<const short8*>(Wp + ((size_t)(nt * KSTEPS + ks) * 64 + lane2) * 8);
        *reinterpret_cast<short8*>(&Bs[((ks * 2 + tile) * 64 + lane2) * 8]) = v;
    }

    // Elementwise mapping: thread <-> (row r = tid>>2, unit pair p = tid&3);
    // owns global units ug0 = b*8+2p, ug0+1.  c in registers for all steps.
    int r  = tid >> 2;
    int p  = tid & 3;
    int ug0 = b * 8 + 2 * p;
    float bia0 = biasf[0 * U_ + ug0], bia1 = biasf[0 * U_ + ug0 + 1];
    float bif0 = biasf[1 * U_ + ug0], bif1 = biasf[1 * U_ + ug0 + 1];
    float big0 = biasf[2 * U_ + ug0], big1 = biasf[2 * U_ + ug0 + 1];
    float bio0 = biasf[3 * U_ + ug0], bio1 = biasf[3 * U_ + ug0 + 1];
    float wout0 = outWf[ug0], wout1 = outWf[ug0 + 1];
    float c0 = 0.f, c1 = 0.f;

    int w = tid >> 6, lane = tid & 63;
    int arow = w * 16 + (lane & 15);          // A-operand row (batch index)
    int koff = (lane >> 4) * 8;
    u16* hb0 = h2;                            // ping-pong buffers (both zeroed)
    u16* hb1 = h2 + B_ * U_;
    __syncthreads();

    for (int t = 0; t < T_; t++) {
        u16* hcur = (t & 1) ? hb1 : hb0;
        const u16* hprev = (t & 1) ? hb0 : hb1;
        const u16* xrow = xb + ((size_t)t * B_ + arow) * F_;
        unsigned int wtag = ((unsigned)(t >> 1) & 1u) ^ 1u;                 // write tag
        unsigned int rpat = ((((unsigned)(t - 1) >> 1) & 1u) ^ 1u) * 0x00010001u; // read pattern

        short8 a0 = *reinterpret_cast<const short8*>(xrow + koff);        // ks=0
        short8 a1 = *reinterpret_cast<const short8*>(xrow + 32 + koff);   // ks=1

        // x-part MFMAs issue before the h poll (hidden under IC latency).
        v4f acc0 = {0.f, 0.f, 0.f, 0.f}, acc1 = {0.f, 0.f, 0.f, 0.f};
        acc0 = __builtin_amdgcn_mfma_f32_16x16x32_bf16(a0, *reinterpret_cast<const short8*>(&Bs[((0 * 2 + 0) * 64 + lane) * 8]), acc0, 0, 0, 0);
        acc1 = __builtin_amdgcn_mfma_f32_16x16x32_bf16(a0, *reinterpret_cast<const short8*>(&Bs[((0 * 2 + 1) * 64 + lane) * 8]), acc1, 0, 0, 0);
        acc0 = __builtin_amdgcn_mfma_f32_16x16x32_bf16(a1, *reinterpret_cast<const short8*>(&Bs[((1 * 2 + 0) * 64 + lane) * 8]), acc0, 0, 0, 0);
        acc1 = __builtin_amdgcn_mfma_f32_16x16x32_bf16(a1, *reinterpret_cast<const short8*>(&Bs[((1 * 2 + 1) * 64 + lane) * 8]), acc1, 0, 0, 0);

        // Poll-load h_{t-1}: 16 coherent 16B loads, all in flight, one drain;
        // accept when every dword carries the expected tag (wave-unanimous).
        // R9: s_sleep backoff after a failed round (shorter IC queues).
        i4 f0,f1,f2,f3,f4,f5,f6,f7,f8,f9,f10,f11,f12,f13,f14,f15;
        {
            const void* bp = (const void*)(hprev + (size_t)arow * U_ + koff);
            int spins = 0;
            for (;;) {
                asm volatile(
                    "global_load_dwordx4 %0,  %16, off sc0 sc1\n\t"
                    "global_load_dwordx4 %1,  %16, off offset:64  sc0 sc1\n\t"
                    "global_load_dwordx4 %2,  %16, off offset:128 sc0 sc1\n\t"
                    "global_load_dwordx4 %3,  %16, off offset:192 sc0 sc1\n\t"
                    "global_load_dwordx4 %4,  %16, off offset:256 sc0 sc1\n\t"
                    "global_load_dwordx4 %5,  %16, off offset:320 sc0 sc1\n\t"
                    "global_load_dwordx4 %6,  %16, off offset:384 sc0 sc1\n\t"
                    "global_load_dwordx4 %7,  %16, off offset:448 sc0 sc1\n\t"
                    "global_load_dwordx4 %8,  %16, off offset:512 sc0 sc1\n\t"
                    "global_load_dwordx4 %9,  %16, off offset:576 sc0 sc1\n\t"
                    "global_load_dwordx4 %10, %16, off offset:640 sc0 sc1\n\t"
                    "global_load_dwordx4 %11, %16, off offset:704 sc0 sc1\n\t"
                    "global_load_dwordx4 %12, %16, off offset:768 sc0 sc1\n\t"
                    "global_load_dwordx4 %13, %16, off offset:832 sc0 sc1\n\t"
                    "global_load_dwordx4 %14, %16, off offset:896 sc0 sc1\n\t"
                    "global_load_dwordx4 %15, %16, off offset:960 sc0 sc1\n\t"
                    "s_waitcnt vmcnt(0)"
                    : "=v"(f0), "=v"(f1), "=v"(f2),  "=v"(f3),
                      "=v"(f4), "=v"(f5), "=v"(f6),  "=v"(f7),
                      "=v"(f8), "=v"(f9), "=v"(f10), "=v"(f11),
                      "=v"(f12),"=v"(f13),"=v"(f14), "=v"(f15)
                    : "v"(bp)
                    : "memory");
                if (t == 0) break;            // zeros are the correct h_{-1}
                unsigned bad = 0;
                #define CK(f) bad |= (((unsigned)(f)[0]) ^ rpat) & 0x00010001u; \
                              bad |= (((unsigned)(f)[1]) ^ rpat) & 0x00010001u; \
                              bad |= (((unsigned)(f)[2]) ^ rpat) & 0x00010001u; \
                              bad |= (((unsigned)(f)[3]) ^ rpat) & 0x00010001u;
                CK(f0) CK(f1) CK(f2)  CK(f3)  CK(f4)  CK(f5)  CK(f6)  CK(f7)
                CK(f8) CK(f9) CK(f10) CK(f11) CK(f12) CK(f13) CK(f14) CK(f15)
                #undef CK
                if (__ballot(bad == 0) == ~0ull) break;
                if (++spins > (1 << 14)) break;   // bailout: never hang
                __builtin_amdgcn_s_sleep(4);      // ~256 cyc backoff
            }
        }
        i4 hf[16] = {f0,f1,f2,f3,f4,f5,f6,f7,f8,f9,f10,f11,f12,f13,f14,f15};

        #pragma unroll
        for (int ks = 2; ks < KSTEPS; ks++) {
            short8 ah = *reinterpret_cast<const short8*>(&hf[ks - 2]);
            acc0 = __builtin_amdgcn_mfma_f32_16x16x32_bf16(ah, *reinterpret_cast<const short8*>(&Bs[((ks * 2 + 0) * 64 + lane) * 8]), acc0, 0, 0, 0);
            acc1 = __builtin_amdgcn_mfma_f32_16x16x32_bf16(ah, *reinterpret_cast<const short8*>(&Bs[((ks * 2 + 1) * 64 + lane) * 8]), acc1, 0, 0, 0);
        }

        // D layout: lane holds D[row=(l>>4)*4+rr][col=l&15].  Ping-pong buffer.
        {
            float (*gb)[36] = gbuf[t & 1];
            int col0 = lane & 15;
            int rbase = w * 16 + (lane >> 4) * 4;
            for (int rr = 0; rr < 4; rr++) {
                gb[rbase + rr][col0]      = acc0[rr];
                gb[rbase + rr][16 + col0] = acc1[rr];
            }
        }
        __syncthreads();   // the single per-step barrier

        // Elementwise: this thread's 2 units.  gbuf cols are 4*ui+gate.
        {
            const float* gr = &gbuf[t & 1][r][8 * p];
            float ig0 = sigmoidf_(gr[0] + bia0), fg0 = sigmoidf_(gr[1] + bif0);
            float gc0 = tanhf_(gr[2] + big0),    og0 = sigmoidf_(gr[3] + bio0);
            float ig1 = sigmoidf_(gr[4] + bia1), fg1 = sigmoidf_(gr[5] + bif1);
            float gc1 = tanhf_(gr[6] + big1),    og1 = sigmoidf_(gr[7] + bio1);
            c0 = fg0 * c0 + ig0 * gc0;
            c1 = fg1 * c1 + ig1 * gc1;
            float h0 = og0 * tanhf_(c0);
            float h1 = og1 * tanhf_(c1);

            // Pack with in-band freshness tag in each bf16's LSB.
            unsigned int pk = (unsigned int)(((unsigned)f2bf(h0) & 0xFFFEu) | wtag)
                            | ((unsigned int)(((unsigned)f2bf(h1) & 0xFFFEu) | wtag) << 16);
            void* sp = (void*)(hcur + (size_t)r * U_ + ug0);
            asm volatile("global_store_dword %0, %1, off sc0 sc1"
                         :: "v"(sp), "v"(pk) : "memory");

            // dot partial over this block's 8 units of row r (untagged h).
            float hw = h0 * wout0 + h1 * wout1;
            hw += __shfl_xor(hw, 1, 64);
            hw += __shfl_xor(hw, 2, 64);
            if (p == 0) dp[t & 31][r] = hw;
        }

        // Flush dot partials every 32 steps (extra barrier only here).
        if ((t & 31) == 31) {
            __syncthreads();
            int t0 = t - 31;
            for (int idx = tid; idx < 2048; idx += 256) {
                int tt = idx >> 6, rr = idx & 63;
                atomicAdd(&dot[(size_t)rr * T_ + (t0 + tt)], dp[tt][rr]);
            }
        }
    }
}

// ---------------------------------------------------------------------------
// Kernel 4: finale.  attention collapses to scalars:
//   coef_t = (t==0) ? 1 : sum_{j<t} att_W[t,j];  shift_t = (t==0) ? 0 : att_b[t]
//   out[b,t] = sigmoid(coef_t * dot[b,t] + shift_t * sum(out_W) + out_b)
// grid = 256 (one block per t).  Output dtype follows the input dtype flag.
// ---------------------------------------------------------------------------
__global__ __launch_bounds__(256) void finale(const float* __restrict__ attWf,
                                              const float* __restrict__ attbf,
                                              const float* __restrict__ outWf,
                                              const float* __restrict__ outbf,
                                              const float* __restrict__ dot,
                                              const int* __restrict__ flag,
                                              void* __restrict__ out) {
    __shared__ float red[256];
    int t = blockIdx.x, tid = threadIdx.x;
    int fg = *flag;

    float v = (tid < t) ? attWf[(size_t)t * T_ + tid] : 0.f;
    red[tid] = v; __syncthreads();
    for (int s = 128; s > 0; s >>= 1) { if (tid < s) red[tid] += red[tid + s]; __syncthreads(); }
    float coef = (t == 0) ? 1.f : red[0];
    __syncthreads();
    red[tid] = outWf[tid] + outWf[tid + 256]; __syncthreads();
    for (int s = 128; s > 0; s >>= 1) { if (tid < s) red[tid] += red[tid + s]; __syncthreads(); }
    float sumW = red[0];

    float base = ((t == 0) ? 0.f : attbf[t]) * sumW + outbf[0];

    if (tid < B_) {
        float s = sigmoidf_(coef * dot[(size_t)tid * T_ + t] + base);
        size_t idx = (size_t)tid * T_ + t;
        if (fg) ((float*)out)[idx] = s;
        else    ((u16*)out)[idx] = f2bf(s);
    }
}

// ---------------------------------------------------------------------------
extern "C" void kernel_launch(void* const* d_in, const int* in_sizes, int n_in,
                              void* d_out, int out_size, void* d_ws, size_t ws_size,
                              hipStream_t stream) {
    const void* x    = d_in[0];
    const void* kin  = d_in[1];
    const void* krec = d_in[2];
    const void* bias = d_in[3];
    const void* attW = d_in[4];
    const void* attb = d_in[5];
    const void* outW = d_in[6];
    const void* outb = d_in[7];

    if (ws_size < (size_t)WS_NEED) return;

    char* ws = (char*)d_ws;
    int*   flag  = (int*)(ws + WS_FLAG);
    u16*   xb    = (u16*)(ws + WS_XB);
    u16*   Wp    = (u16*)(ws + WS_WP);
    u16*   h2    = (u16*)(ws + WS_H2);
    float* dot   = (float*)(ws + WS_DOT);
    float* biasf = (float*)(ws + WS_BIASF);
    float* attWf = (float*)(ws + WS_ATTWF);
    float* attbf = (float*)(ws + WS_ATTBF);
    float* outWf = (float*)(ws + WS_OUTWF);
    float* outbf = (float*)(ws + WS_OUTBF);

    detect<<<1, 256, 0, stream>>>((const unsigned int*)kin, flag);
    convert<<<4556, 256, 0, stream>>>(x, bias, attW, attb, outW, outb, flag,
                                      xb, biasf, attWf, attbf, outWf, outbf, dot,
                                      (unsigned int*)h2);
    pack_w<<<576, 256, 0, stream>>>(kin, krec, flag, Wp);
    lstm_persist<<<64, 256, 0, stream>>>(xb, biasf, outWf, Wp, h2, dot);
    finale<<<256, 256, 0, stream>>>(attWf, attbf, outWf, outbf, dot, flag, d_out);
}

// Round 10
// 686.523 us; speedup vs baseline: 7.8863x; 1.8081x over previous
//
#include <hip/hip_runtime.h>
#include <hip/hip_bf16.h>
#include <string.h>

// Problem constants
#define B_ 64
#define T_ 256
#define F_ 64
#define U_ 512
#define G4_ 2048     // 4*U
#define KTOT 576     // F + U
#define KSTEPS 18    // KTOT/32

typedef __attribute__((ext_vector_type(8))) short short8;
typedef __attribute__((ext_vector_type(4))) float v4f;
typedef __attribute__((ext_vector_type(4))) int i4;
typedef unsigned short u16;

__device__ __forceinline__ float bf2f(u16 b) {
    unsigned int x = ((unsigned int)b) << 16;
    float f; memcpy(&f, &x, 4); return f;
}
__device__ __forceinline__ u16 f2bf(float f) {
    __hip_bfloat16 h = __float2bfloat16(f);
    u16 b; memcpy(&b, &h, 2); return b;
}
__device__ __forceinline__ float sigmoidf_(float x) { return 1.f / (1.f + __expf(-x)); }
__device__ __forceinline__ float tanhf_(float x) {   // clamped exp form (R8/R9-proven)
    float xc = fminf(15.f, fmaxf(-15.f, x));
    float e = __expf(2.f * xc);
    return (e - 1.f) / (e + 1.f);
}

// Dtype-flexible element load: fg=1 -> fp32, fg=0 -> bf16.
__device__ __forceinline__ float ldany(const void* p, size_t i, int fg) {
    return fg ? ((const float*)p)[i] : bf2f(((const u16*)p)[i]);
}

// Workspace layout (bytes; offsets 64-aligned) -- unchanged from R9.
#define WS_FLAG   0             // int dtype-flag @0
#define WS_XB     64            // bf16 [T][B][F]          2,097,152
#define WS_WP     2097216       // bf16 packed weights     2,359,296
#define WS_H2     4456512       // bf16 [2][B][U]            131,072
#define WS_DOT    4718656       // fp32 [B][T]                65,536
#define WS_BIASF  4784192       // fp32 [4U]                   8,192
#define WS_ATTWF  4792384       // fp32 [T][T]               262,144
#define WS_ATTBF  5054528       // fp32 [T]                    1,024
#define WS_OUTWF  5055552       // fp32 [U]                    2,048
#define WS_OUTBF  5057600       // fp32 [1]                       64
#define WS_NEED   5057920

// ---------------------------------------------------------------------------
// Kernel 0: dtype detection (flag: 1 = fp32 inputs, 0 = bf16).
// ---------------------------------------------------------------------------
__global__ __launch_bounds__(256) void detect(const unsigned int* __restrict__ w,
                                              int* __restrict__ flag) {
    __shared__ int votes;
    if (threadIdx.x == 0) votes = 0;
    __syncthreads();
    unsigned int v = w[threadIdx.x];
    int e = (v >> 7) & 0xFF;
    if (e >= 100 && e <= 135) atomicAdd(&votes, 1);
    __syncthreads();
    if (threadIdx.x == 0) *flag = (votes < 200) ? 1 : 0;
}

// ---------------------------------------------------------------------------
// Kernel 1: canonicalize inputs.  x -> xb bf16 [T][B][F]; small arrays ->
// fp32; dot -> 0; h2 ping-pong -> 0 (tag 0 == stale for every expected tag;
// zeros are also the correct h_{-1} at t=0 where the check is skipped).
// ---------------------------------------------------------------------------
__global__ __launch_bounds__(256) void convert(const void* __restrict__ x,
                                               const void* __restrict__ bias,
                                               const void* __restrict__ attW,
                                               const void* __restrict__ attb,
                                               const void* __restrict__ outW,
                                               const void* __restrict__ outb,
                                               const int* __restrict__ flag,
                                               u16* __restrict__ xb,
                                               float* __restrict__ biasf,
                                               float* __restrict__ attWf,
                                               float* __restrict__ attbf,
                                               float* __restrict__ outWf,
                                               float* __restrict__ outbf,
                                               float* __restrict__ dot,
                                               unsigned int* __restrict__ h2z) {
    int fg = *flag;
    size_t i = (size_t)blockIdx.x * 256 + threadIdx.x;
    if (i < 1048576) {
        float v = ldany(x, i, fg);
        int b = (int)(i >> 14), t = (int)((i >> 6) & 255), f = (int)(i & 63);
        xb[((size_t)t * B_ + b) * F_ + f] = f2bf(v);
        return;
    }
    i -= 1048576;
    if (i < 2048)  { biasf[i] = ldany(bias, i, fg); return; }
    i -= 2048;
    if (i < 65536) { attWf[i] = ldany(attW, i, fg); return; }
    i -= 65536;
    if (i < 256)   { attbf[i] = ldany(attb, i, fg); return; }
    i -= 256;
    if (i < 512)   { outWf[i] = ldany(outW, i, fg); return; }
    i -= 512;
    if (i < 1)     { outbf[i] = ldany(outb, i, fg); return; }
    i -= 1;
    if (i < 16384) { dot[i] = 0.f; return; }
    i -= 16384;
    if (i < 32768) { h2z[i] = 0u; return; }   // both h ping-pong buffers
}

// ---------------------------------------------------------------------------
// Kernel 2: pack [kernel; rec_kernel] into MFMA-B fragments, cols c'=4u+gate.
// Lane l of fragment (nt, ks) supplies B[k=ks*32+(l>>4)*8+j][col=nt*16+(l&15)].
// ---------------------------------------------------------------------------
__global__ __launch_bounds__(256) void pack_w(const void* __restrict__ kin,
                                              const void* __restrict__ krec,
                                              const int* __restrict__ flag,
                                              u16* __restrict__ Wp) {
    int fg = *flag;
    int gid = blockIdx.x * 256 + threadIdx.x;   // grid = 576*256 == 128*18*64
    int lane = gid & 63;
    int frag = gid >> 6;
    int nt = frag / KSTEPS;
    int ks = frag - nt * KSTEPS;
    int kbase = ks * 32 + (lane >> 4) * 8;
    int cp = nt * 16 + (lane & 15);
    int u = cp >> 2, gate = cp & 3;
    int C = gate * U_ + u;
    short8 v;
    for (int j = 0; j < 8; j++) {
        int k = kbase + j;
        float w = (k < F_) ? ldany(kin, (size_t)k * G4_ + C, fg)
                           : ldany(krec, (size_t)(k - F_) * G4_ + C, fg);
        v[j] = (short)f2bf(w);
    }
    *reinterpret_cast<short8*>(Wp + (size_t)gid * 8) = v;
}

// ---------------------------------------------------------------------------
// Kernel 3: PERSISTENT LSTM, LOW-POLL-TRAFFIC PARTITION.
// Grid 64 blocks x 512 threads (8 waves).  Block = (rg = bid&3: 16 batch
// rows) x (gu = bid>>2: 32 hidden units).  Wave w owns global n-tile
// gu*8+w; its 18 B-fragments live in 144 VGPRs (loaded once; NO weight LDS).
// h exchange (same R7/R9-proven sc1+in-band-LSB-tag mechanism): the block
// polls only ITS 16 rows (16 KB) -- wave w polls local rows 2w,2w+1 with 2
// coherent 16B loads/lane -- and stages them into LDS for A-fragments.
// Chip-wide poll traffic: 1 MB/round vs R9's 4 MB (the measured inflator).
// Two __syncthreads/step: stage-ready, gbuf-ready (single-buffer stage/gbuf
// safe: stage writes(t+1) occur after barrier2(t) > all stage reads(t);
// gbuf writes(t+1) occur after barrier1(t+1) > all gbuf reads(t)).
// c: 1 register/thread (thread = row x unit).
// ---------------------------------------------------------------------------
__global__ __launch_bounds__(512, 2) void lstm_persist(const u16* __restrict__ xb,
                                                       const float* __restrict__ biasf,
                                                       const float* __restrict__ outWf,
                                                       const u16* __restrict__ Wp,
                                                       u16* __restrict__ h2,
                                                       float* __restrict__ dot) {
    __shared__ __align__(16) u16 stage[16 * 520];   // 16 rows x 512 h (+8 pad) = 16.3 KB
    __shared__ __align__(16) float gbuf[16][132];   // 16 rows x 128 gate cols (+4 pad)
    __shared__ float dp[32][16];                    // dot partials: 32 steps x 16 rows

    int tid = threadIdx.x;
    int bid = blockIdx.x;
    int rg = bid & 3;                     // row-group: rows [16rg, 16rg+16)
    int gu = bid >> 2;                    // unit-group: units [32gu, 32gu+32)
    int w = tid >> 6, l = tid & 63;
    int nt = gu * 8 + w;                  // this wave's global n-tile

    // Weights into VGPRs: 18 fragments (144 VGPRs), loaded once.
    short8 W[KSTEPS];
    #pragma unroll
    for (int ks = 0; ks < KSTEPS; ks++)
        W[ks] = *reinterpret_cast<const short8*>(Wp + ((size_t)(nt * KSTEPS + ks) * 64 + l) * 8);

    // MFMA roles.
    int arow = rg * 16 + (l & 15);        // A row (global batch index)
    int koff = (l >> 4) * 8;              // k-chunk within a 32-wide ks
    // Poll/stage roles: wave w handles local rows 2w, 2w+1.
    int plr = 2 * w + (l >> 5);           // local row polled by this lane
    int pcol = (l & 31) * 16;             // u16 column of this lane's 32B chunk
    // Elementwise roles: thread = (row = tid>>5, ui = tid&31).
    int er = tid >> 5;
    int ui = tid & 31;
    int unit = gu * 32 + ui;
    float bia = biasf[0 * U_ + unit], bif = biasf[1 * U_ + unit];
    float big = biasf[2 * U_ + unit], bio = biasf[3 * U_ + unit];
    float wout = outWf[unit];
    float c = 0.f;

    for (int t = 0; t < T_; t++) {
        u16* hcur = h2 + (size_t)(t & 1) * (B_ * U_);
        const u16* hprev = h2 + (size_t)((t + 1) & 1) * (B_ * U_);
        unsigned int wtag = ((unsigned)(t >> 1) & 1u) ^ 1u;
        unsigned int rpat = ((((unsigned)(t - 1) >> 1) & 1u) ^ 1u) * 0x00010001u;

        // Poll this wave's 2 rows of h_{t-1}: 2 coherent 16B loads per lane,
        // accept when all 8 dwords are fresh wave-unanimously.
        i4 q0, q1;
        {
            const void* bp = (const void*)(hprev + (size_t)(rg * 16 + plr) * U_ + pcol);
            int spins = 0;
            for (;;) {
                asm volatile(
                    "global_load_dwordx4 %0, %2, off sc0 sc1\n\t"
                    "global_load_dwordx4 %1, %2, off offset:16 sc0 sc1\n\t"
                    "s_waitcnt vmcnt(0)"
                    : "=v"(q0), "=v"(q1) : "v"(bp) : "memory");
                if (t == 0) break;        // zeros are the correct h_{-1}
                unsigned bad = 0;
                bad |= (((unsigned)q0[0]) ^ rpat) & 0x00010001u;
                bad |= (((unsigned)q0[1]) ^ rpat) & 0x00010001u;
                bad |= (((unsigned)q0[2]) ^ rpat) & 0x00010001u;
                bad |= (((unsigned)q0[3]) ^ rpat) & 0x00010001u;
                bad |= (((unsigned)q1[0]) ^ rpat) & 0x00010001u;
                bad |= (((unsigned)q1[1]) ^ rpat) & 0x00010001u;
                bad |= (((unsigned)q1[2]) ^ rpat) & 0x00010001u;
                bad |= (((unsigned)q1[3]) ^ rpat) & 0x00010001u;
                if (__ballot(bad == 0) == ~0ull) break;
                if (++spins > (1 << 14)) break;   // bailout: never hang
                __builtin_amdgcn_s_sleep(2);      // short backoff
            }
        }
        // Stage into LDS (row-major, 520-u16 stride to break bank aliasing).
        *reinterpret_cast<i4*>(&stage[plr * 520 + pcol])     = q0;
        *reinterpret_cast<i4*>(&stage[plr * 520 + pcol + 8]) = q1;
        __syncthreads();   // barrier 1: stage ready

        // MFMA: x-part from global (L2-hot), h-part from staged LDS.
        // Two independent 9-chains to pipeline the accumulator.
        const u16* xrow = xb + ((size_t)t * B_ + arow) * F_;
        short8 a0 = *reinterpret_cast<const short8*>(xrow + koff);
        short8 a1 = *reinterpret_cast<const short8*>(xrow + 32 + koff);
        v4f acc0 = {0.f, 0.f, 0.f, 0.f}, acc1 = {0.f, 0.f, 0.f, 0.f};
        acc0 = __builtin_amdgcn_mfma_f32_16x16x32_bf16(a0, W[0], acc0, 0, 0, 0);
        acc1 = __builtin_amdgcn_mfma_f32_16x16x32_bf16(a1, W[1], acc1, 0, 0, 0);
        #pragma unroll
        for (int ks = 2; ks < KSTEPS; ks += 2) {
            short8 ah0 = *reinterpret_cast<const short8*>(
                &stage[(l & 15) * 520 + (ks - 2) * 32 + koff]);
            short8 ah1 = *reinterpret_cast<const short8*>(
                &stage[(l & 15) * 520 + (ks - 1) * 32 + koff]);
            acc0 = __builtin_amdgcn_mfma_f32_16x16x32_bf16(ah0, W[ks],     acc0, 0, 0, 0);
            acc1 = __builtin_amdgcn_mfma_f32_16x16x32_bf16(ah1, W[ks + 1], acc1, 0, 0, 0);
        }
        v4f acc = acc0 + acc1;

        // D layout: lane holds D[row=(l>>4)*4+rr][col=l&15] -> gbuf cols 16w+col.
        {
            int col0 = 16 * w + (l & 15);
            int rb = (l >> 4) * 4;
            #pragma unroll
            for (int rr = 0; rr < 4; rr++)
                gbuf[rb + rr][col0] = acc[rr];
        }
        __syncthreads();   // barrier 2: gbuf ready

        // Elementwise: 1 unit per thread.  gbuf cols are 4*ui+gate.
        {
            const float* gr = &gbuf[er][4 * ui];
            float ig = sigmoidf_(gr[0] + bia);
            float fg = sigmoidf_(gr[1] + bif);
            float gc = tanhf_(gr[2] + big);
            float og = sigmoidf_(gr[3] + bio);
            c = fg * c + ig * gc;
            float h = og * tanhf_(c);

            // Pack unit pair into a dword with LSB tags; even-ui lane stores.
            float hp = __shfl_xor(h, 1, 64);
            if ((ui & 1) == 0) {
                unsigned int pk = (unsigned int)(((unsigned)f2bf(h)  & 0xFFFEu) | wtag)
                                | ((unsigned int)(((unsigned)f2bf(hp) & 0xFFFEu) | wtag) << 16);
                void* sp = (void*)(hcur + (size_t)(rg * 16 + er) * U_ + unit);
                asm volatile("global_store_dword %0, %1, off sc0 sc1"
                             :: "v"(sp), "v"(pk) : "memory");
            }

            // dot partial over this block's 32 units of row er.
            float s = h * wout;
            s += __shfl_xor(s, 1, 64);
            s += __shfl_xor(s, 2, 64);
            s += __shfl_xor(s, 4, 64);
            s += __shfl_xor(s, 8, 64);
            s += __shfl_xor(s, 16, 64);
            if (ui == 0) dp[t & 31][er] = s;
        }

        // Flush dot partials every 32 steps (512 entries, 1 per thread).
        if ((t & 31) == 31) {
            __syncthreads();
            int t0 = t - 31;
            int tt = tid >> 4, row = tid & 15;
            atomicAdd(&dot[(size_t)(rg * 16 + row) * T_ + (t0 + tt)], dp[tt][row]);
        }
    }
}

// ---------------------------------------------------------------------------
// Kernel 4: finale.  attention collapses to scalars:
//   coef_t = (t==0) ? 1 : sum_{j<t} att_W[t,j];  shift_t = (t==0) ? 0 : att_b[t]
//   out[b,t] = sigmoid(coef_t * dot[b,t] + shift_t * sum(out_W) + out_b)
// grid = 256 (one block per t).  Output dtype follows the input dtype flag.
// ---------------------------------------------------------------------------
__global__ __launch_bounds__(256) void finale(const float* __restrict__ attWf,
                                              const float* __restrict__ attbf,
                                              const float* __restrict__ outWf,
                                              const float* __restrict__ outbf,
                                              const float* __restrict__ dot,
                                              const int* __restrict__ flag,
                                              void* __restrict__ out) {
    __shared__ float red[256];
    int t = blockIdx.x, tid = threadIdx.x;
    int fg = *flag;

    float v = (tid < t) ? attWf[(size_t)t * T_ + tid] : 0.f;
    red[tid] = v; __syncthreads();
    for (int s = 128; s > 0; s >>= 1) { if (tid < s) red[tid] += red[tid + s]; __syncthreads(); }
    float coef = (t == 0) ? 1.f : red[0];
    __syncthreads();
    red[tid] = outWf[tid] + outWf[tid + 256]; __syncthreads();
    for (int s = 128; s > 0; s >>= 1) { if (tid < s) red[tid] += red[tid + s]; __syncthreads(); }
    float sumW = red[0];

    float base = ((t == 0) ? 0.f : attbf[t]) * sumW + outbf[0];

    if (tid < B_) {
        float s = sigmoidf_(coef * dot[(size_t)tid * T_ + t] + base);
        size_t idx = (size_t)tid * T_ + t;
        if (fg) ((float*)out)[idx] = s;
        else    ((u16*)out)[idx] = f2bf(s);
    }
}

// ---------------------------------------------------------------------------
extern "C" void kernel_launch(void* const* d_in, const int* in_sizes, int n_in,
                              void* d_out, int out_size, void* d_ws, size_t ws_size,
                              hipStream_t stream) {
    const void* x    = d_in[0];
    const void* kin  = d_in[1];
    const void* krec = d_in[2];
    const void* bias = d_in[3];
    const void* attW = d_in[4];
    const void* attb = d_in[5];
    const void* outW = d_in[6];
    const void* outb = d_in[7];

    if (ws_size < (size_t)WS_NEED) return;

    char* ws = (char*)d_ws;
    int*   flag  = (int*)(ws + WS_FLAG);
    u16*   xb    = (u16*)(ws + WS_XB);
    u16*   Wp    = (u16*)(ws + WS_WP);
    u16*   h2    = (u16*)(ws + WS_H2);
    float* dot   = (float*)(ws + WS_DOT);
    float* biasf = (float*)(ws + WS_BIASF);
    float* attWf = (float*)(ws + WS_ATTWF);
    float* attbf = (float*)(ws + WS_ATTBF);
    float* outWf = (float*)(ws + WS_OUTWF);
    float* outbf = (float*)(ws + WS_OUTBF);

    detect<<<1, 256, 0, stream>>>((const unsigned int*)kin, flag);
    convert<<<4556, 256, 0, stream>>>(x, bias, attW, attb, outW, outb, flag,
                                      xb, biasf, attWf, attbf, outWf, outbf, dot,
                                      (unsigned int*)h2);
    pack_w<<<576, 256, 0, stream>>>(kin, krec, flag, Wp);
    lstm_persist<<<64, 512, 0, stream>>>(xb, biasf, outWf, Wp, h2, dot);
    finale<<<256, 256, 0, stream>>>(attWf, attbf, outWf, outbf, dot, flag, d_out);
}